// Round 1
// baseline (2150.530 us; speedup 1.0000x reference)
//
#include <hip/hip_runtime.h>
#include <hip/hip_bf16.h>
#include <stdint.h>

#define VOCAB 50257
#define VPAD  50304
#define DEMB  512
#define RES   2048
#define ROUT  512
#define BB    8
#define TT    256
#define BT    2048
#define SLOTS 80
#define RBLK  32
#define UPB   64

typedef _Float16 half8 __attribute__((ext_vector_type(8)));
typedef float f32x4 __attribute__((ext_vector_type(4)));

// async global->LDS, 16B per lane; LDS dest is wave-uniform base + lane*16
__device__ __forceinline__ void g2lds16(const _Float16* g, _Float16* l) {
  __builtin_amdgcn_global_load_lds((const __attribute__((address_space(1))) void*)g,
                                   (__attribute__((address_space(3))) void*)l,
                                   16, 0, 0);
}

// ---------------- prep: casts / gather / transpose / h0 broadcast ----------------
__global__ __launch_bounds__(256)
void prep_k(const int* __restrict__ x, const float* __restrict__ temb,
            const float* __restrict__ Win, const float* __restrict__ Wb,
            const float* __restrict__ Wa, const float* __restrict__ h0,
            _Float16* __restrict__ Aemb, _Float16* __restrict__ Wt,
            _Float16* __restrict__ Wb16, _Float16* __restrict__ Wa16,
            _Float16* __restrict__ hbuf) {
  const int gt = blockIdx.x * 256 + threadIdx.x;
  const int gs = gridDim.x * 256;
  for (int i = gt; i < BT * DEMB; i += gs) {
    int bt = i >> 9, d = i & 511;
    Aemb[i] = (_Float16)temb[(size_t)x[bt] * DEMB + d];
  }
  for (int i = gt; i < RES * DEMB; i += gs) {   // Wt[r][d] = Win[d][r]
    int rr = i >> 9, d = i & 511;
    Wt[i] = (_Float16)Win[(size_t)d * RES + rr];
  }
  for (int i = gt; i < ROUT * RES; i += gs) Wb16[i] = (_Float16)Wb[i];
  for (int i = gt; i < VPAD * ROUT; i += gs)
    Wa16[i] = (i < VOCAB * ROUT) ? (_Float16)Wa[i] : (_Float16)0.f;
  for (int i = gt; i < RES * BB; i += gs) hbuf[i] = (_Float16)h0[i >> 3];
}

// ---------------- build ELL of W_rec (block per row, ballot compaction) ----------------
__global__ __launch_bounds__(256)
void build_ell_k(const float* __restrict__ Wrec, float* __restrict__ evals,
                 unsigned short* __restrict__ ecols, int* __restrict__ ecnt) {
  __shared__ int base;
  const int r = blockIdx.x;
  if (threadIdx.x == 0) base = 0;
  __syncthreads();
  const float* row = Wrec + (size_t)r * RES;
  const int lane = threadIdx.x & 63;
  for (int j0 = 0; j0 < RES; j0 += 256) {
    int j = j0 + threadIdx.x;
    float v = row[j];
    bool nz = (v != 0.f);
    unsigned long long mask = __ballot(nz);
    int pre = __popcll(mask & ((1ull << lane) - 1ull));
    int tot = __popcll(mask);
    int wb = 0;
    if (lane == 0 && tot) wb = atomicAdd(&base, tot);
    wb = __shfl(wb, 0);
    if (nz) {
      int slot = wb + pre;
      if (slot < SLOTS) {
        evals[(size_t)r * SLOTS + slot] = v;
        ecols[(size_t)r * SLOTS + slot] = (unsigned short)j;
      }
    }
  }
  __syncthreads();
  if (threadIdx.x == 0) ecnt[r] = (base <= SLOTS) ? base : SLOTS;
}

// ---------------- persistent sparse recurrence: 32 blocks, flag sync per step ----------------
__global__ __launch_bounds__(256)
void recurrence_k(const float* __restrict__ ep, const float* __restrict__ evals,
                  const unsigned short* __restrict__ ecols, const int* __restrict__ ecnt,
                  const float* __restrict__ a, const float* __restrict__ h0,
                  _Float16* __restrict__ hbuf, _Float16* __restrict__ hs,
                  int* __restrict__ scnt) {
  __shared__ __align__(16) _Float16 hcur[RES * BB];           // 32 KB, [unit][batch] f16
  __shared__ float vals[UPB * (SLOTS + 1)];                   // pitch 81: bank-conflict-free
  __shared__ unsigned short cols[UPB * (SLOTS + 1)];
  __shared__ float hown[UPB][BB];                             // fp32 carry state (this block's units)
  __shared__ float aa[UPB];
  __shared__ int cnts[UPB];

  const int tid = threadIdx.x;
  const int u0 = blockIdx.x * UPB;
  const int ul = tid >> 2;          // 0..63 local unit
  const int g  = tid & 3;           // slot group / batch-pair selector

  for (int i = tid; i < UPB * SLOTS; i += 256) {
    int u = i / SLOTS, s = i - u * SLOTS;
    vals[u * (SLOTS + 1) + s] = evals[(size_t)(u0 + u) * SLOTS + s];
    cols[u * (SLOTS + 1) + s] = ecols[(size_t)(u0 + u) * SLOTS + s];
  }
  if (tid < UPB) { aa[tid] = a[u0 + tid]; cnts[tid] = ecnt[u0 + tid]; }
  for (int i = tid; i < UPB * BB; i += 256) hown[i >> 3][i & 7] = h0[u0 + (i >> 3)];
  __syncthreads();

  for (int t = 0; t < TT; ++t) {
    if (t > 0) {
      if (tid == 0) {
        while (__hip_atomic_load(&scnt[t], __ATOMIC_RELAXED, __HIP_MEMORY_SCOPE_AGENT) < RBLK)
          __builtin_amdgcn_s_sleep(4);
        __threadfence();   // acquire: invalidate L1/L2 so staged h is fresh cross-XCD
      }
      __syncthreads();
    }
    // stage full h_t (32 KB f16) into LDS
    {
      const _Float16* src = hbuf + (size_t)(t & 1) * (RES * BB);
      #pragma unroll
      for (int r = 0; r < 8; ++r)
        g2lds16(src + (r * 256 + tid) * 8, hcur + (r * 256 + (tid & ~63)) * 8);
    }
    __syncthreads();

    // sparse gather: thread (ul,g) does slots g, g+4, ... for all 8 batches
    float acc[BB];
    #pragma unroll
    for (int b = 0; b < BB; ++b) acc[b] = 0.f;
    const int ns = cnts[ul];
    for (int s = g; s < ns; s += 4) {
      float wv = vals[ul * (SLOTS + 1) + s];
      int c = cols[ul * (SLOTS + 1) + s];
      half8 hv = *(const half8*)(hcur + c * BB);
      #pragma unroll
      for (int b = 0; b < BB; ++b) acc[b] += wv * (float)hv[b];
    }
    // butterfly over the 4 slot-groups (lane bits 0..1)
    #pragma unroll
    for (int b = 0; b < BB; ++b) {
      acc[b] += __shfl_xor(acc[b], 1);
      acc[b] += __shfl_xor(acc[b], 2);
    }
    // each thread updates batches {2g, 2g+1} of its unit
    _Float16* dst = hbuf + (size_t)((t + 1) & 1) * (RES * BB);
    #pragma unroll
    for (int q = 0; q < 2; ++q) {
      int b = 2 * g + q;
      float epv = ep[((size_t)b * TT + t) * RES + u0 + ul];
      float pre = epv + acc[b];
      pre = fminf(10.f, fmaxf(-10.f, pre));
      float al = aa[ul];
      float hn = (1.f - al) * hown[ul][b] + al * tanhf(pre);
      hown[ul][b] = hn;
      _Float16 h16 = (_Float16)hn;
      dst[(size_t)(u0 + ul) * BB + b] = h16;
      hs[((size_t)b * TT + t) * RES + u0 + ul] = h16;
    }
    __syncthreads();                 // all waves' stores drained (vmcnt0 at barrier)
    if (tid == 0) {
      __threadfence();               // release: write back L2 so other XCDs see h_{t+1}
      __hip_atomic_fetch_add(&scnt[t + 1], 1, __ATOMIC_RELAXED, __HIP_MEMORY_SCOPE_AGENT);
    }
  }
}

// ---------------- f16 MFMA GEMM: C[M,N] = A[M,K] @ B^T (B stored [N][K]) ----------------
// MODE 0: f32 out; MODE 1: f32 out + bias + col<Ncheck guard; MODE 2: f16 out
template <int MODE>
__global__ __launch_bounds__(256)
void gemm_bt(const _Float16* __restrict__ A, const _Float16* __restrict__ B,
             float* __restrict__ Cf, _Float16* __restrict__ Ch,
             const float* __restrict__ bias, int Nld, int Ncheck, int K) {
  __shared__ __align__(16) _Float16 sA[128 * 64];
  __shared__ __align__(16) _Float16 sB[128 * 64];
  const int tid = threadIdx.x;
  const int m0 = blockIdx.x * 128, n0 = blockIdx.y * 128;
  const int lane = tid & 63, w = tid >> 6;
  const int wm = (w & 1) << 6, wn = (w >> 1) << 6;
  const int lrow = lane & 15, quad = lane >> 4;

  f32x4 acc[4][4];
  #pragma unroll
  for (int i = 0; i < 4; ++i)
    #pragma unroll
    for (int j = 0; j < 4; ++j) acc[i][j] = (f32x4){0.f, 0.f, 0.f, 0.f};

  const _Float16* Ab = A + (size_t)m0 * K;
  const _Float16* Bb = B + (size_t)n0 * K;
  const int kt_n = K >> 6;
  for (int kt = 0; kt < kt_n; ++kt) {
    const int k0 = kt << 6;
    // stage 128x64 A and B tiles; k8 group XOR-swizzled by row for conflict-free ds_read_b128
    #pragma unroll
    for (int r = 0; r < 4; ++r) {
      int s = (r << 8) + tid;                 // group index 0..1023
      int row = s >> 3;
      int k8 = (s & 7) ^ (row & 7);
      g2lds16(Ab + (size_t)row * K + k0 + (k8 << 3), sA + ((s & ~63) << 3));
      g2lds16(Bb + (size_t)row * K + k0 + (k8 << 3), sB + ((s & ~63) << 3));
    }
    __syncthreads();
    #pragma unroll
    for (int kk = 0; kk < 2; ++kk) {
      half8 af[4], bf[4];
      #pragma unroll
      for (int i = 0; i < 4; ++i) {
        int ra = wm + (i << 4) + lrow;
        af[i] = *(const half8*)(sA + (((ra << 3) + (((kk << 2) + quad) ^ (ra & 7))) << 3));
        int rb = wn + (i << 4) + lrow;
        bf[i] = *(const half8*)(sB + (((rb << 3) + (((kk << 2) + quad) ^ (rb & 7))) << 3));
      }
      #pragma unroll
      for (int i = 0; i < 4; ++i)
        #pragma unroll
        for (int j = 0; j < 4; ++j)
          acc[i][j] = __builtin_amdgcn_mfma_f32_16x16x32_f16(af[i], bf[j], acc[i][j], 0, 0, 0);
    }
    __syncthreads();
  }
  #pragma unroll
  for (int i = 0; i < 4; ++i) {
    const int row = m0 + wm + (i << 4) + (quad << 2);
    #pragma unroll
    for (int j = 0; j < 4; ++j) {
      const int col = n0 + wn + (j << 4) + lrow;
      f32x4 v = acc[i][j];
      if (MODE == 1) {
        if (col < Ncheck) {
          const float bv = bias[col];
          #pragma unroll
          for (int r2 = 0; r2 < 4; ++r2)
            Cf[(size_t)(row + r2) * Nld + col] = v[r2] + bv;
        }
      } else if (MODE == 0) {
        #pragma unroll
        for (int r2 = 0; r2 < 4; ++r2) Cf[(size_t)(row + r2) * Nld + col] = v[r2];
      } else {
        #pragma unroll
        for (int r2 = 0; r2 < 4; ++r2) Ch[(size_t)(row + r2) * Nld + col] = (_Float16)v[r2];
      }
    }
  }
}

extern "C" void kernel_launch(void* const* d_in, const int* in_sizes, int n_in,
                              void* d_out, int out_size, void* d_ws, size_t ws_size,
                              hipStream_t stream) {
  const int*   x    = (const int*)d_in[0];
  const float* temb = (const float*)d_in[1];
  const float* Win  = (const float*)d_in[2];
  const float* Wrec = (const float*)d_in[3];
  const float* a    = (const float*)d_in[4];
  const float* Wb   = (const float*)d_in[5];
  const float* Wa   = (const float*)d_in[6];
  const float* bias = (const float*)d_in[7];
  const float* h0   = (const float*)d_in[8];
  float* out = (float*)d_out;
  (void)in_sizes; (void)n_in; (void)out_size; (void)ws_size;

  char* p = (char*)d_ws;
  auto take = [&](size_t bytes) -> char* {
    char* r = p;
    p += (bytes + 255) & ~(size_t)255;
    return r;
  };
  _Float16* Aemb = (_Float16*)take((size_t)BT * DEMB * 2);
  _Float16* Wt   = (_Float16*)take((size_t)RES * DEMB * 2);
  _Float16* Wb16 = (_Float16*)take((size_t)ROUT * RES * 2);
  _Float16* Wa16 = (_Float16*)take((size_t)VPAD * ROUT * 2);
  _Float16* proj = (_Float16*)take((size_t)BT * ROUT * 2);
  float*    ep   = (float*)   take((size_t)BT * RES * 4);
  _Float16* hs   = (_Float16*)take((size_t)BT * RES * 2);
  _Float16* hbuf = (_Float16*)take((size_t)2 * RES * BB * 2);
  float*    evals= (float*)   take((size_t)RES * SLOTS * 4);
  unsigned short* ecols = (unsigned short*)take((size_t)RES * SLOTS * 2);
  int*      ecnt = (int*)take((size_t)RES * 4);
  int*      scnt = (int*)take((size_t)(TT + 1) * 4);

  hipMemsetAsync(scnt, 0, (TT + 1) * sizeof(int), stream);
  prep_k<<<dim3(2048), 256, 0, stream>>>(x, temb, Win, Wb, Wa, h0, Aemb, Wt, Wb16, Wa16, hbuf);
  build_ell_k<<<dim3(RES), 256, 0, stream>>>(Wrec, evals, ecols, ecnt);
  // ep = Aemb @ Wt^T   (M=2048, N=2048, K=512)
  gemm_bt<0><<<dim3(16, 16), 256, 0, stream>>>(Aemb, Wt, ep, nullptr, nullptr, RES, RES, DEMB);
  recurrence_k<<<dim3(RBLK), 256, 0, stream>>>(ep, evals, ecols, ecnt, a, h0, hbuf, hs, scnt);
  // proj = hs @ Wb16^T (M=2048, N=512, K=2048), f16 out
  gemm_bt<2><<<dim3(16, 4), 256, 0, stream>>>(hs, Wb16, nullptr, proj, nullptr, ROUT, ROUT, RES);
  // logits = proj @ Wa16^T + bias (M=2048, N=50304->50257, K=512)
  gemm_bt<1><<<dim3(16, 393), 256, 0, stream>>>(proj, Wa16, out, nullptr, bias, VOCAB, VOCAB, ROUT);
}